// Round 7
// baseline (216.523 us; speedup 1.0000x reference)
//
#include <hip/hip_runtime.h>
#include <stdint.h>

typedef _Float16 half_t;
typedef __attribute__((ext_vector_type(8))) _Float16 f16x8;
typedef __attribute__((ext_vector_type(4))) _Float16 f16x4;
typedef __attribute__((ext_vector_type(4))) float f32x4;

#define SQN 4096
#define SKN 16448
#define NROPE 16384
#define NSPLIT 16
#define NTILES 514          // 16448 / 32
#define SCQ 0.090168441360f // log2(e) / 16  (folded into Q at proj time)

// async global->LDS, 16B per lane; LDS dest = wave-uniform base + lane*16
#define GLD16(gp, lp) __builtin_amdgcn_global_load_lds( \
    (const __attribute__((address_space(1))) void*)(const void*)(gp), \
    (__attribute__((address_space(3))) void*)(void*)(lp), 16, 0, 0)

// ---------------- weight transpose: W[k][n] f32 -> WT[n][k] f16 (4 mats) ------
__global__ __launch_bounds__(256) void wt_kernel(const float* __restrict__ qw,
    const float* __restrict__ kw, const float* __restrict__ vw, const float* __restrict__ ow,
    half_t* __restrict__ wt)
{
    __shared__ float tile[64][65];
    int b = blockIdx.x;
    int mat = b >> 4, t4 = b & 15;
    int k0 = (t4 >> 2) << 6, n0 = (t4 & 3) << 6;
    const float* W = (mat == 0) ? qw : (mat == 1) ? kw : (mat == 2) ? vw : ow;
    half_t* WT = wt + mat * 65536;
    int t = threadIdx.x;
#pragma unroll
    for (int j = 0; j < 16; ++j) {
        int e = j * 256 + t;
        tile[e >> 6][e & 63] = W[(k0 + (e >> 6)) * 256 + n0 + (e & 63)];
    }
    __syncthreads();
#pragma unroll
    for (int j = 0; j < 16; ++j) {
        int e = j * 256 + t;
        WT[(n0 + (e >> 6)) * 256 + k0 + (e & 63)] = (half_t)tile[e & 63][e >> 6];
    }
}

// ---------------- fused QKV projection + bias + RoPE -------------------------
// grid: 64 (Q) + 257 (K) + 257 (V) = 578 blocks, 256 threads (4 waves x 16 rows)
__global__ __launch_bounds__(256) void proj_kernel(
    const float* __restrict__ query, const float* __restrict__ key, const float* __restrict__ value,
    const float* __restrict__ cosp, const float* __restrict__ sinp,
    const half_t* __restrict__ wt,
    const float* __restrict__ qb, const float* __restrict__ kb, const float* __restrict__ vb,
    half_t* __restrict__ Qe, half_t* __restrict__ Ke, half_t* __restrict__ VTb)
{
    __shared__ __align__(16) half_t S[64 * 264];    // [row][d pad 264] for Q/K path

    int b = blockIdx.x;
    int mode; long row0;
    const float* X; const half_t* W; const float* bias;
    if (b < 64)       { mode = 0; row0 = (long)b * 64;         X = query; W = wt;           bias = qb; }
    else if (b < 321) { mode = 1; row0 = (long)(b - 64) * 64;  X = key;   W = wt + 65536;   bias = kb; }
    else              { mode = 2; row0 = (long)(b - 321) * 64; X = value; W = wt + 131072;  bias = vb; }

    int tid = threadIdx.x;
    int w = tid >> 6, l = tid & 63;
    int l16 = l & 15, l4 = l >> 4;
    long rw0 = row0 + w * 16;

    f32x4 acc[16];
#pragma unroll
    for (int i = 0; i < 16; ++i) acc[i] = (f32x4){0.f, 0.f, 0.f, 0.f};

    const float* xrow = X + (rw0 + l16) * 256;
    for (int ks = 0; ks < 8; ++ks) {
        f32x4 xa = *reinterpret_cast<const f32x4*>(xrow + ks * 32 + l4 * 8);
        f32x4 xb = *reinterpret_cast<const f32x4*>(xrow + ks * 32 + l4 * 8 + 4);
        f16x8 af;
#pragma unroll
        for (int j = 0; j < 4; ++j) { af[j] = (half_t)xa[j]; af[4 + j] = (half_t)xb[j]; }
#pragma unroll
        for (int nt = 0; nt < 16; ++nt) {
            f16x8 bf = *reinterpret_cast<const f16x8*>(W + (nt * 16 + l16) * 256 + ks * 32 + l4 * 8);
            acc[nt] = __builtin_amdgcn_mfma_f32_16x16x32_f16(af, bf, acc[nt], 0, 0, 0);
        }
    }

    bool dorope = (mode == 0) || (mode == 1 && row0 < NROPE);
#pragma unroll
    for (int nt = 0; nt < 16; ++nt) {
        int d = nt * 16 + l16;
        float bv = bias[d];
        f32x4 v = acc[nt];
#pragma unroll
        for (int r = 0; r < 4; ++r) v[r] += bv;
        if (dorope) {
#pragma unroll
            for (int r = 0; r < 4; ++r) {
                long m = rw0 + l4 * 4 + r;
                long crow = (mode == 0) ? m : (m >> 2);
                float c = cosp[crow * 256 + d];
                float s = sinp[crow * 256 + d];
                float val = v[r];
                float other = __shfl_xor(val, 1);
                float rot = (d & 1) ? other : -other;
                v[r] = val * c + rot * s;
                if (mode == 0) v[r] *= SCQ;     // fold softmax scale into Q
            }
        }
        if (mode == 2) {        // direct tiled store: VTb[kvb][d][kv&31]
            long kv = rw0 + l4 * 4;
            long kvb = kv >> 5;
            int  kvw = (int)(kv & 31);
            f16x4 pk;
#pragma unroll
            for (int r = 0; r < 4; ++r) pk[r] = (half_t)v[r];
            *reinterpret_cast<f16x4*>(VTb + kvb * 8192 + (long)d * 32 + kvw) = pk;
        } else {                // stage to LDS for coalesced row-major store
            int wrow = w * 16 + l4 * 4;
#pragma unroll
            for (int r = 0; r < 4; ++r)
                S[(wrow + r) * 264 + d] = (half_t)v[r];
        }
    }

    if (mode != 2) {
        __syncthreads();
        half_t* O = ((mode == 0) ? Qe : Ke) + row0 * 256;
#pragma unroll
        for (int i = 0; i < 8; ++i) {
            int e = (i * 256 + tid) * 8;        // 64 rows x 256 d, 16B chunks
            int row = e >> 8, col = e & 255;
            f16x8 val = *reinterpret_cast<const f16x8*>(&S[row * 264 + col]);
            *reinterpret_cast<f16x8*>(O + e) = val;
        }
    }
}

// ---------------- flash attention: 32 q-rows/wave, double-buffered DMA -------
// grid: 512 blocks (chunk = b&15 -> XCD-pinned pair; qb = b>>4), 256 threads.
// Each wave owns 32 q-rows (two 16-row halves). Every K/V fragment read from
// LDS feeds TWO MFMAs -> LDS bytes per q-row halved vs R6 (which measured at
// ~93% of LDS BW peak = the R6 bottleneck).
__global__ __launch_bounds__(256, 2) void flash_kernel(
    const half_t* __restrict__ Qe, const half_t* __restrict__ Ke, const half_t* __restrict__ VTb,
    half_t* __restrict__ AOp, float* __restrict__ Lse)
{
    __shared__ __align__(16) half_t Ks[2][32 * 256];   // 2 x 16 KB, swizzled content
    __shared__ __align__(16) half_t Vs[2][256 * 32];   // 2 x 16 KB, linear tile
    __shared__ __align__(16) half_t Ps[4][2][16 * 40]; // per-wave, per-half P (10 KB)

    int b = blockIdx.x;
    int chunk = b & 15;          // XCD x holds chunks {x, x+8}: ~2.1MB L2 slice
    int qb = b >> 4;
    int tid = threadIdx.x;
    int w = tid >> 6, l = tid & 63;
    int l16 = l & 15, l4 = l >> 4;
    long qw0 = (long)qb * 128 + w * 32;

    int t0 = (NTILES * chunk) / NSPLIT;
    int t1 = (NTILES * (chunk + 1)) / NSPLIT;

    f16x8 qf0[8], qf1[8];   // Q (pre-scaled) B-operands for the two 16-row halves
#pragma unroll
    for (int ks = 0; ks < 8; ++ks) {
        qf0[ks] = *reinterpret_cast<const f16x8*>(Qe + (qw0 + l16) * 256 + ks * 32 + l4 * 8);
        qf1[ks] = *reinterpret_cast<const f16x8*>(Qe + (qw0 + 16 + l16) * 256 + ks * 32 + l4 * 8);
    }

    f32x4 o0[16], o1[16];
#pragma unroll
    for (int i = 0; i < 16; ++i) {
        o0[i] = (f32x4){0.f, 0.f, 0.f, 0.f};
        o1[i] = (f32x4){0.f, 0.f, 0.f, 0.f};
    }
    float mrun0 = -3.0e38f, lsum0 = 0.0f;
    float mrun1 = -3.0e38f, lsum1 = 0.0f;

    // DMA stage of tile t into buffer d_: wave w fills bytes [w*4K,(w+1)*4K)
#define STAGE(d_, t) do {                                                    \
        const half_t* kb_ = Ke + (long)(t) * 8192;                           \
        const half_t* vb_ = VTb + (long)(t) * 8192;                          \
        half_t* ksd = &Ks[d_][0];                                            \
        half_t* vsd = &Vs[d_][0];                                            \
        _Pragma("unroll")                                                    \
        for (int j = 0; j < 4; ++j) {                                        \
            int pb = w * 4096 + j * 1024;                                    \
            int p  = pb + l * 16;                                            \
            int row = p >> 9;                                                \
            int cols = ((p >> 4) & 31) ^ (row & 7);                          \
            GLD16(kb_ + row * 256 + cols * 8, ksd + (pb >> 1));              \
            GLD16(vb_ + (p >> 1), vsd + (pb >> 1));                          \
        }                                                                    \
    } while (0)

    STAGE(0, t0);
    asm volatile("s_waitcnt vmcnt(0)" ::: "memory");
    __builtin_amdgcn_s_barrier();

    half_t* Pw0 = &Ps[w][0][0];
    half_t* Pw1 = &Ps[w][1][0];
    const int xk = l16 & 7;
    int cur = 0;

    for (int t = t0; t < t1; ++t) {
        if (t + 1 < t1) STAGE(cur ^ 1, t + 1);   // issue next-tile DMA FIRST

        const half_t* KsC = &Ks[0][0] + cur * (32 * 256);
        const half_t* VsC = &Vs[0][0] + cur * (256 * 32);

        // joint QK^T for both halves: each K fragment feeds 2 MFMAs
        f32x4 s00 = (f32x4){0.f, 0.f, 0.f, 0.f};
        f32x4 s01 = (f32x4){0.f, 0.f, 0.f, 0.f};
        f32x4 s10 = (f32x4){0.f, 0.f, 0.f, 0.f};
        f32x4 s11 = (f32x4){0.f, 0.f, 0.f, 0.f};
#pragma unroll
        for (int ks = 0; ks < 8; ++ks) {
            int slot = ((ks * 4 + l4) ^ xk) << 3;
            f16x8 ka0 = *reinterpret_cast<const f16x8*>(KsC + l16 * 256 + slot);
            f16x8 ka1 = *reinterpret_cast<const f16x8*>(KsC + (16 + l16) * 256 + slot);
            s00 = __builtin_amdgcn_mfma_f32_16x16x32_f16(ka0, qf0[ks], s00, 0, 0, 0);
            s01 = __builtin_amdgcn_mfma_f32_16x16x32_f16(ka1, qf0[ks], s01, 0, 0, 0);
            s10 = __builtin_amdgcn_mfma_f32_16x16x32_f16(ka0, qf1[ks], s10, 0, 0, 0);
            s11 = __builtin_amdgcn_mfma_f32_16x16x32_f16(ka1, qf1[ks], s11, 0, 0, 0);
        }

        // ---- softmax half 0 ----
        {
            float tv[8];
#pragma unroll
            for (int r = 0; r < 4; ++r) { tv[r] = s00[r]; tv[4 + r] = s01[r]; }
            float pm = tv[0];
#pragma unroll
            for (int i = 1; i < 8; ++i) pm = fmaxf(pm, tv[i]);
            pm = fmaxf(pm, __shfl_xor(pm, 16));
            pm = fmaxf(pm, __shfl_xor(pm, 32));
            if (!__all(pm - mrun0 <= 8.0f)) {
                float mn = fmaxf(mrun0, pm);
                float alpha = __builtin_amdgcn_exp2f(mrun0 - mn);
                lsum0 *= alpha;
                float ao[4];
#pragma unroll
                for (int r = 0; r < 4; ++r) ao[r] = __shfl(alpha, l4 * 4 + r);
#pragma unroll
                for (int i = 0; i < 16; ++i)
#pragma unroll
                    for (int r = 0; r < 4; ++r) o0[i][r] *= ao[r];
                mrun0 = mn;
            }
            float p[8];
            float psum = 0.f;
#pragma unroll
            for (int i = 0; i < 8; ++i) { p[i] = __builtin_amdgcn_exp2f(tv[i] - mrun0); psum += p[i]; }
            psum += __shfl_xor(psum, 16);
            psum += __shfl_xor(psum, 32);
            lsum0 += psum;
            f16x4 pk0, pk1;
#pragma unroll
            for (int r = 0; r < 4; ++r) { pk0[r] = (half_t)p[r]; pk1[r] = (half_t)p[4 + r]; }
            *reinterpret_cast<f16x4*>(Pw0 + l16 * 40 + l4 * 4) = pk0;
            *reinterpret_cast<f16x4*>(Pw0 + l16 * 40 + 16 + l4 * 4) = pk1;
        }
        // ---- softmax half 1 ----
        {
            float tv[8];
#pragma unroll
            for (int r = 0; r < 4; ++r) { tv[r] = s10[r]; tv[4 + r] = s11[r]; }
            float pm = tv[0];
#pragma unroll
            for (int i = 1; i < 8; ++i) pm = fmaxf(pm, tv[i]);
            pm = fmaxf(pm, __shfl_xor(pm, 16));
            pm = fmaxf(pm, __shfl_xor(pm, 32));
            if (!__all(pm - mrun1 <= 8.0f)) {
                float mn = fmaxf(mrun1, pm);
                float alpha = __builtin_amdgcn_exp2f(mrun1 - mn);
                lsum1 *= alpha;
                float ao[4];
#pragma unroll
                for (int r = 0; r < 4; ++r) ao[r] = __shfl(alpha, l4 * 4 + r);
#pragma unroll
                for (int i = 0; i < 16; ++i)
#pragma unroll
                    for (int r = 0; r < 4; ++r) o1[i][r] *= ao[r];
                mrun1 = mn;
            }
            float p[8];
            float psum = 0.f;
#pragma unroll
            for (int i = 0; i < 8; ++i) { p[i] = __builtin_amdgcn_exp2f(tv[i] - mrun1); psum += p[i]; }
            psum += __shfl_xor(psum, 16);
            psum += __shfl_xor(psum, 32);
            lsum1 += psum;
            f16x4 pk0, pk1;
#pragma unroll
            for (int r = 0; r < 4; ++r) { pk0[r] = (half_t)p[r]; pk1[r] = (half_t)p[4 + r]; }
            *reinterpret_cast<f16x4*>(Pw1 + l16 * 40 + l4 * 4) = pk0;
            *reinterpret_cast<f16x4*>(Pw1 + l16 * 40 + 16 + l4 * 4) = pk1;
        }

        // joint PV: each V fragment feeds 2 MFMAs
        f16x8 pa0 = *reinterpret_cast<const f16x8*>(Pw0 + l16 * 40 + l4 * 8);
        f16x8 pa1 = *reinterpret_cast<const f16x8*>(Pw1 + l16 * 40 + l4 * 8);
#pragma unroll
        for (int nt = 0; nt < 16; ++nt) {
            f16x8 vbf = *reinterpret_cast<const f16x8*>(VsC + (nt * 16 + l16) * 32 + l4 * 8);
            o0[nt] = __builtin_amdgcn_mfma_f32_16x16x32_f16(pa0, vbf, o0[nt], 0, 0, 0);
            o1[nt] = __builtin_amdgcn_mfma_f32_16x16x32_f16(pa1, vbf, o1[nt], 0, 0, 0);
        }

        asm volatile("s_waitcnt vmcnt(0)" ::: "memory");
        __builtin_amdgcn_s_barrier();
        cur ^= 1;
    }
#undef STAGE

    // epilogue: normalized f16 partials + LSE (v_log_f32 = log2)
    {
        float inv[4];
#pragma unroll
        for (int r = 0; r < 4; ++r) inv[r] = 1.0f / __shfl(lsum0, l4 * 4 + r);
        half_t* Ab = AOp + ((long)chunk * SQN + qw0) * 256;
#pragma unroll
        for (int nt = 0; nt < 16; ++nt)
#pragma unroll
            for (int r = 0; r < 4; ++r)
                Ab[(l4 * 4 + r) * 256 + nt * 16 + l16] = (half_t)(o0[nt][r] * inv[r]);
        if (l < 16)
            Lse[(long)chunk * SQN + qw0 + l16] = mrun0 + __builtin_amdgcn_logf(lsum0);
    }
    {
        float inv[4];
#pragma unroll
        for (int r = 0; r < 4; ++r) inv[r] = 1.0f / __shfl(lsum1, l4 * 4 + r);
        half_t* Ab = AOp + ((long)chunk * SQN + qw0 + 16) * 256;
#pragma unroll
        for (int nt = 0; nt < 16; ++nt)
#pragma unroll
            for (int r = 0; r < 4; ++r)
                Ab[(l4 * 4 + r) * 256 + nt * 16 + l16] = (half_t)(o1[nt][r] * inv[r]);
        if (l < 16)
            Lse[(long)chunk * SQN + qw0 + 16 + l16] = mrun1 + __builtin_amdgcn_logf(lsum1);
    }
}

// ---------------- fused reduce + O projection --------------------------------
// grid: 256 blocks x 256 thr; block -> 16 rows, wave w -> cols w*64..+64.
// A-fragment = LSE-weighted sum of the 16 AOp chunks, built in registers.
__global__ __launch_bounds__(256) void oproj_kernel(
    const half_t* __restrict__ AOp, const float* __restrict__ Lse,
    const half_t* __restrict__ WTo, const float* __restrict__ ob,
    float* __restrict__ out)
{
    int b = blockIdx.x;
    int tid = threadIdx.x;
    int w = tid >> 6, l = tid & 63;
    int l16 = l & 15, l4 = l >> 4;
    long row = (long)b * 16 + l16;

    float ls[NSPLIT];
    float lmax = -3.0e38f;
#pragma unroll
    for (int c = 0; c < NSPLIT; ++c) { ls[c] = Lse[(long)c * SQN + row]; lmax = fmaxf(lmax, ls[c]); }
    float wgt[NSPLIT];
    float wsum = 0.f;
#pragma unroll
    for (int c = 0; c < NSPLIT; ++c) { wgt[c] = __builtin_amdgcn_exp2f(ls[c] - lmax); wsum += wgt[c]; }
    float invw = 1.0f / wsum;
#pragma unroll
    for (int c = 0; c < NSPLIT; ++c) wgt[c] *= invw;

    f32x4 acc[4];
#pragma unroll
    for (int i = 0; i < 4; ++i) acc[i] = (f32x4){0.f, 0.f, 0.f, 0.f};

#pragma unroll
    for (int ks = 0; ks < 8; ++ks) {
        float facc[8];
#pragma unroll
        for (int j = 0; j < 8; ++j) facc[j] = 0.f;
#pragma unroll
        for (int c = 0; c < NSPLIT; ++c) {
            f16x8 v = *reinterpret_cast<const f16x8*>(
                AOp + ((long)c * SQN + row) * 256 + ks * 32 + l4 * 8);
#pragma unroll
            for (int j = 0; j < 8; ++j) facc[j] += wgt[c] * (float)v[j];
        }
        f16x8 af;
#pragma unroll
        for (int j = 0; j < 8; ++j) af[j] = (half_t)facc[j];
#pragma unroll
        for (int nt = 0; nt < 4; ++nt) {
            f16x8 bf = *reinterpret_cast<const f16x8*>(
                WTo + ((w * 4 + nt) * 16 + l16) * 256 + ks * 32 + l4 * 8);
            acc[nt] = __builtin_amdgcn_mfma_f32_16x16x32_f16(af, bf, acc[nt], 0, 0, 0);
        }
    }

    long r0 = (long)b * 16;
#pragma unroll
    for (int nt = 0; nt < 4; ++nt) {
        int d = (w * 4 + nt) * 16 + l16;
        float bv = ob[d];
#pragma unroll
        for (int r = 0; r < 4; ++r)
            out[(r0 + l4 * 4 + r) * 256 + d] = acc[nt][r] + bv;
    }
}

extern "C" void kernel_launch(void* const* d_in, const int* in_sizes, int n_in,
                              void* d_out, int out_size, void* d_ws, size_t ws_size,
                              hipStream_t stream) {
    const float* query = (const float*)d_in[0];
    const float* key   = (const float*)d_in[1];
    const float* value = (const float*)d_in[2];
    const float* cosp  = (const float*)d_in[3];
    const float* sinp  = (const float*)d_in[4];
    const float* qw = (const float*)d_in[5];
    const float* qb = (const float*)d_in[6];
    const float* kw = (const float*)d_in[7];
    const float* kb = (const float*)d_in[8];
    const float* vw = (const float*)d_in[9];
    const float* vb = (const float*)d_in[10];
    const float* ow = (const float*)d_in[11];
    const float* ob = (const float*)d_in[12];

    char* ws = (char*)d_ws;
    half_t* Qe  = (half_t*)(ws);                     // 4096*256*2       = 2,097,152
    half_t* Ke  = (half_t*)(ws + 2097152);           // 16448*256*2      = 8,421,376
    half_t* VTb = (half_t*)(ws + 10518528);          // 514*256*32*2     = 8,421,376
    half_t* WT  = (half_t*)(ws + 18939904);          // 4*256*256*2      = 524,288
    half_t* AOp = (half_t*)(ws + 19464192);          // 16*4096*256*2    = 33,554,432
    float*  Lse = (float*)(ws + 53018624);           // 16*4096*4        = 262,144
    // total ws use: 53,280,768 bytes (< 55,377,920 proven)

    hipLaunchKernelGGL(wt_kernel, dim3(64), dim3(256), 0, stream, qw, kw, vw, ow, WT);
    hipLaunchKernelGGL(proj_kernel, dim3(578), dim3(256), 0, stream,
                       query, key, value, cosp, sinp, WT, qb, kb, vb, Qe, Ke, VTb);
    hipLaunchKernelGGL(flash_kernel, dim3(512), dim3(256), 0, stream, Qe, Ke, VTb, AOp, Lse);
    hipLaunchKernelGGL(oproj_kernel, dim3(256), dim3(256), 0, stream, AOp, Lse, WT + 3 * 65536, ob, (float*)d_out);
}